// Round 9
// baseline (197.746 us; speedup 1.0000x reference)
//
#include <hip/hip_runtime.h>
#include <hip/hip_bf16.h>

#define S_LEN 8192
#define E_DIM 64
#define NCONV (63 * 8191)
#define KSPLIT 16
#define KRANGE (S_LEN / KSPLIT)
#define SVT (S_LEN + 32)   // vT_bf row stride (shorts): breaks L1 set aliasing
#define KTS 72             // kt LDS row stride (shorts)
#define VTS 40             // vt LDS row stride (shorts)
#define PS  40             // pT LDS row stride (shorts)

typedef short short8 __attribute__((ext_vector_type(8)));
typedef float f32x4 __attribute__((ext_vector_type(4)));

__device__ __forceinline__ float ldin(const void* __restrict__ p, int i, int f32flag) {
    return f32flag ? ((const float*)p)[i]
                   : __bfloat162float(((const __hip_bfloat16*)p)[i]);
}
__device__ __forceinline__ float bfbits2f(unsigned int u16bits) {
    union { unsigned int u; float f; } c; c.u = u16bits << 16; return c.f;
}
__device__ __forceinline__ unsigned short f2bfu(float f) {
    __hip_bfloat16 h = __float2bfloat16(f);
    union { __hip_bfloat16 h; unsigned short u; } c; c.h = h; return c.u;
}
__device__ __forceinline__ int hw_bad(unsigned short h) {
    const unsigned int e = (h >> 7) & 0xFF;
    return !(h == 0 || h == 0x8000 || (e >= 0x60 && e <= 0x86));
}

// ---------------- Kernel 1: fused QKV projection (32 rows/block) + conv + counter init ----------------
// blocks 0..255: qkv, 32 rows each (weights staged once, 2 chunks of 16 rows).
// blocks 256..319: conv partial sums; block 256 zeroes the counters.
__global__ __launch_bounds__(256) void qkv_conv(
    const void* __restrict__ x,
    const void* __restrict__ conv_w, const void* __restrict__ conv_b,
    const void* __restrict__ Wq, const void* __restrict__ bq,
    const void* __restrict__ Wk, const void* __restrict__ bk,
    const void* __restrict__ Wv, const void* __restrict__ bv,
    unsigned short* __restrict__ q_bf, unsigned short* __restrict__ k_bf,
    unsigned short* __restrict__ vT_bf, float* __restrict__ conv_part,
    int* __restrict__ counters)   // [0..31]=qcnt, [32]=fincnt
{
    __shared__ int s_fx, s_fw;
    const int tid = threadIdx.x;
    if (tid == 0) { s_fx = 0; s_fw = 0; }
    __syncthreads();
    if (tid < 64) { if (hw_bad(((const unsigned short*)x)[tid])) atomicOr(&s_fx, 1); }
    else if (tid < 128) { if (hw_bad(((const unsigned short*)Wq)[tid - 64])) atomicOr(&s_fw, 1); }
    __syncthreads();
    const int fx = s_fx, fw = s_fw;

    if (blockIdx.x >= 256) {   // ---- conv path ----
        const int bid = blockIdx.x - 256;
        if (bid == 0 && tid < 33) counters[tid] = 0;
        const float c0 = ldin(conv_w, 0, fw), c1 = ldin(conv_w, 1, fw);
        const float c2 = ldin(conv_w, 2, fw), c3 = ldin(conv_w, 3, fw);
        const float cb = ldin(conv_b, 0, fw);
        float acc = 0.f;
        for (int idx = bid * 256 + tid; idx < NCONV; idx += 64 * 256) {
            const int h = idx % 63;
            const int w = idx / 63;
            const float z = c0 * ldin(x, w * 64 + h, fx)     + c1 * ldin(x, (w + 1) * 64 + h, fx)
                          + c2 * ldin(x, w * 64 + h + 1, fx) + c3 * ldin(x, (w + 1) * 64 + h + 1, fx)
                          + cb;
            acc += 1.f / (1.f + __expf(-z));
        }
        for (int off = 32; off > 0; off >>= 1) acc += __shfl_down(acc, off);
        __shared__ float wsum[4];
        if ((tid & 63) == 0) wsum[tid >> 6] = acc;
        __syncthreads();
        if (tid == 0) conv_part[bid] = wsum[0] + wsum[1] + wsum[2] + wsum[3];
        return;
    }

    // ---- qkv path: weights once, 2 row-chunks ----
    __shared__ float wsh[3][4096];   // 48 KB
    __shared__ float xT[64 * 16];
    __shared__ float bsh[3][64];
    __shared__ float vs[64 * 17];
    const void* Ws[3] = { Wq, Wk, Wv };
    const void* Bs[3] = { bq, bk, bv };
#pragma unroll
    for (int w = 0; w < 3; ++w) {
        if (fw) {
            const float4* src = (const float4*)Ws[w];
            for (int i = tid; i < 1024; i += 256) {
                float4 v = src[i];
                float* d = &wsh[w][i * 4];
                d[0] = v.x; d[1] = v.y; d[2] = v.z; d[3] = v.w;
            }
            if (tid < 64) bsh[w][tid] = ((const float*)Bs[w])[tid];
        } else {
            const uint4* src = (const uint4*)Ws[w];
            for (int i = tid; i < 512; i += 256) {
                uint4 v = src[i];
                float* d = &wsh[w][i * 8];
                d[0] = bfbits2f(v.x & 0xffff); d[1] = bfbits2f(v.x >> 16);
                d[2] = bfbits2f(v.y & 0xffff); d[3] = bfbits2f(v.y >> 16);
                d[4] = bfbits2f(v.z & 0xffff); d[5] = bfbits2f(v.z >> 16);
                d[6] = bfbits2f(v.w & 0xffff); d[7] = bfbits2f(v.w >> 16);
            }
            if (tid < 64) bsh[w][tid] = bfbits2f(((const unsigned short*)Bs[w])[tid]);
        }
    }

#pragma unroll
    for (int ch = 0; ch < 2; ++ch) {
        const int row0 = blockIdx.x * 32 + ch * 16;
        __syncthreads();   // first: orders wsh; later: protects xT/vs reuse
        for (int idx = tid; idx < 1024; idx += 256) {
            const int r = idx >> 6, i = idx & 63;
            xT[i * 16 + r] = ldin(x, (row0 + r) * 64 + i, fx);
        }
        __syncthreads();

        const int e = tid & 63, rg = tid >> 6;
        float aq[4], ak[4], av[4];
#pragma unroll
        for (int r = 0; r < 4; ++r) { aq[r] = bsh[0][e]; ak[r] = bsh[1][e]; av[r] = bsh[2][e]; }
#pragma unroll 8
        for (int i = 0; i < 64; ++i) {
            const float4 xv = *(const float4*)&xT[i * 16 + rg * 4];
            const float wq = wsh[0][i * 64 + e], wk = wsh[1][i * 64 + e], wv = wsh[2][i * 64 + e];
            aq[0] += xv.x * wq; aq[1] += xv.y * wq; aq[2] += xv.z * wq; aq[3] += xv.w * wq;
            ak[0] += xv.x * wk; ak[1] += xv.y * wk; ak[2] += xv.z * wk; ak[3] += xv.w * wk;
            av[0] += xv.x * wv; av[1] += xv.y * wv; av[2] += xv.z * wv; av[3] += xv.w * wv;
        }
#pragma unroll
        for (int r = 0; r < 4; ++r) {
            const int row = row0 + rg * 4 + r;
            q_bf[row * 64 + e] = f2bfu(aq[r]);
            k_bf[row * 64 + e] = f2bfu(ak[r]);
            vs[e * 17 + rg * 4 + r] = av[r];
        }
        __syncthreads();
        {
            const int e2 = tid >> 2, rp = (tid & 3) * 4;
            const unsigned short h0 = f2bfu(vs[e2 * 17 + rp + 0]);
            const unsigned short h1 = f2bfu(vs[e2 * 17 + rp + 1]);
            const unsigned short h2 = f2bfu(vs[e2 * 17 + rp + 2]);
            const unsigned short h3 = f2bfu(vs[e2 * 17 + rp + 3]);
            uint2 pk;
            pk.x = (unsigned int)h0 | ((unsigned int)h1 << 16);
            pk.y = (unsigned int)h2 | ((unsigned int)h3 << 16);
            *(uint2*)(vT_bf + (size_t)e2 * SVT + row0 + rp) = pk;
        }
    }
}

// ---------------- Kernel 2: MFMA flash attention + fused cross-split reduction tail ----------------
__global__ __launch_bounds__(256) void attn_bf(
    const unsigned short* __restrict__ q_bf, const unsigned short* __restrict__ k_bf,
    const unsigned short* __restrict__ vT_bf,
    unsigned short* __restrict__ o_split, float* __restrict__ l_split,
    int* __restrict__ counters, float* __restrict__ pool_part,
    const float* __restrict__ conv_part,
    const void* __restrict__ Wp, const void* __restrict__ bp,
    const void* __restrict__ x, const void* __restrict__ Wq,
    void* __restrict__ out)
{
    __shared__ unsigned short kt[2][32 * KTS];    //  9216 B
    __shared__ unsigned short vt[2][64 * VTS];    // 10240 B
    __shared__ unsigned short pTs[4][4][16 * PS]; // 20480 B
    const int tid = threadIdx.x;
    const int wave = tid >> 6, lane = tid & 63;
    const int ln = lane & 15, quad = lane >> 4;
    const int qrow0 = blockIdx.x * 256 + wave * 64;
    const int kbase = blockIdx.y * KRANGE;

    short8 aQ[4][2];
#pragma unroll
    for (int T = 0; T < 4; ++T) {
        aQ[T][0] = *(const short8*)(q_bf + (qrow0 + 16 * T + ln) * 64 + quad * 8);
        aQ[T][1] = *(const short8*)(q_bf + (qrow0 + 16 * T + ln) * 64 + 32 + quad * 8);
    }

    const f32x4 zero = {0.f, 0.f, 0.f, 0.f};
    f32x4 acc[4][4];
    float l_acc[4][4];
#pragma unroll
    for (int T = 0; T < 4; ++T)
#pragma unroll
        for (int n = 0; n < 4; ++n) { acc[T][n] = zero; l_acc[T][n] = 0.f; }

    const int krow = tid >> 3, kch = tid & 7;
    const int vrow = tid >> 2, vch = tid & 3;
    uint4 kreg, vreg;

    {
        const uint4 k0 = *(const uint4*)(k_bf + (size_t)(kbase + krow) * 64 + kch * 8);
        const uint4 v0 = *(const uint4*)(vT_bf + (size_t)vrow * SVT + kbase + vch * 8);
        *(uint4*)(&kt[0][krow * KTS + kch * 8]) = k0;
        *(uint4*)(&vt[0][vrow * VTS + vch * 8]) = v0;
        const int key1 = kbase + 32;
        kreg = *(const uint4*)(k_bf + (size_t)(key1 + krow) * 64 + kch * 8);
        vreg = *(const uint4*)(vT_bf + (size_t)vrow * SVT + key1 + vch * 8);
    }
    __syncthreads();

    const int nIter = KRANGE >> 5;
#pragma unroll 2
    for (int kc = 0; kc < nIter; ++kc) {
        const int cur = kc & 1;
        if (kc + 1 < nIter) {
            *(uint4*)(&kt[cur ^ 1][krow * KTS + kch * 8]) = kreg;
            *(uint4*)(&vt[cur ^ 1][vrow * VTS + vch * 8]) = vreg;
        }
        if (kc + 2 < nIter) {
            const int key2 = kbase + (kc + 2) * 32;
            kreg = *(const uint4*)(k_bf + (size_t)(key2 + krow) * 64 + kch * 8);
            vreg = *(const uint4*)(vT_bf + (size_t)vrow * SVT + key2 + vch * 8);
        }
        const unsigned short* ktc = &kt[cur][0];
        const unsigned short* vtc = &vt[cur][0];
        const short8 bE0 = *(const short8*)(ktc + (2 * ln) * KTS + quad * 8);
        const short8 bE1 = *(const short8*)(ktc + (2 * ln) * KTS + 32 + quad * 8);
        const short8 bO0 = *(const short8*)(ktc + (2 * ln + 1) * KTS + quad * 8);
        const short8 bO1 = *(const short8*)(ktc + (2 * ln + 1) * KTS + 32 + quad * 8);
        const short8 v0 = *(const short8*)(vtc + (0 * 16 + ln) * VTS + quad * 8);
        const short8 v1 = *(const short8*)(vtc + (1 * 16 + ln) * VTS + quad * 8);
        const short8 v2 = *(const short8*)(vtc + (2 * 16 + ln) * VTS + quad * 8);
        const short8 v3 = *(const short8*)(vtc + (3 * 16 + ln) * VTS + quad * 8);

        f32x4 scE[4], scO[4];
#pragma unroll
        for (int T = 0; T < 4; ++T) {
            scE[T] = __builtin_amdgcn_mfma_f32_16x16x32_bf16(aQ[T][0], bE0, zero, 0, 0, 0);
            scE[T] = __builtin_amdgcn_mfma_f32_16x16x32_bf16(aQ[T][1], bE1, scE[T], 0, 0, 0);
            scO[T] = __builtin_amdgcn_mfma_f32_16x16x32_bf16(aQ[T][0], bO0, zero, 0, 0, 0);
            scO[T] = __builtin_amdgcn_mfma_f32_16x16x32_bf16(aQ[T][1], bO1, scO[T], 0, 0, 0);
        }
#pragma unroll
        for (int T = 0; T < 4; ++T) {
            unsigned short* w = &pTs[wave][T][0];
#pragma unroll
            for (int r = 0; r < 4; ++r) {
                const float pE = __expf(scE[T][r] * 0.125f);
                const float pO = __expf(scO[T][r] * 0.125f);
                l_acc[T][r] += pE + pO;
                const unsigned int pk = (unsigned int)f2bfu(pE) | ((unsigned int)f2bfu(pO) << 16);
                *(unsigned int*)(w + (quad * 4 + r) * PS + 2 * ln) = pk;
            }
        }
#pragma unroll
        for (int T = 0; T < 4; ++T) {
            const short8 aP = *(const short8*)(&pTs[wave][T][ln * PS + quad * 8]);
            acc[T][0] = __builtin_amdgcn_mfma_f32_16x16x32_bf16(aP, v0, acc[T][0], 0, 0, 0);
            acc[T][1] = __builtin_amdgcn_mfma_f32_16x16x32_bf16(aP, v1, acc[T][1], 0, 0, 0);
            acc[T][2] = __builtin_amdgcn_mfma_f32_16x16x32_bf16(aP, v2, acc[T][2], 0, 0, 0);
            acc[T][3] = __builtin_amdgcn_mfma_f32_16x16x32_bf16(aP, v3, acc[T][3], 0, 0, 0);
        }
        __syncthreads();
    }

    unsigned short* ob = o_split + ((size_t)blockIdx.y * S_LEN + qrow0) * 64;
#pragma unroll
    for (int T = 0; T < 4; ++T) {
#pragma unroll
        for (int r = 0; r < 4; ++r) {
            const int row = 16 * T + quad * 4 + r;
            ob[row * 64 +  0 + ln] = f2bfu(acc[T][0][r]);
            ob[row * 64 + 16 + ln] = f2bfu(acc[T][1][r]);
            ob[row * 64 + 32 + ln] = f2bfu(acc[T][2][r]);
            ob[row * 64 + 48 + ln] = f2bfu(acc[T][3][r]);
        }
#pragma unroll
        for (int r = 0; r < 4; ++r) {
            float v = l_acc[T][r];
            v += __shfl_xor(v, 1); v += __shfl_xor(v, 2);
            v += __shfl_xor(v, 4); v += __shfl_xor(v, 8);
            if (ln == 0)
                l_split[blockIdx.y * S_LEN + qrow0 + 16 * T + quad * 4 + r] = v;
        }
    }

    // ---- fused tail: last-arriving split-block of this q-group reduces all splits ----
    __threadfence();
    __shared__ int s_last;
    if (tid == 0) s_last = (atomicAdd(&counters[blockIdx.x], 1) == KSPLIT - 1) ? 1 : 0;
    __syncthreads();
    if (!s_last) return;
    __threadfence();   // acquire: all split writes visible

    __shared__ float linv[256];
    __shared__ float psh[64];
    const int qb = blockIdx.x * 256;
    {
        float l = 0.f;
#pragma unroll
        for (int s = 0; s < KSPLIT; ++s) l += l_split[s * S_LEN + qb + tid];
        linv[tid] = 1.f / l;
    }
    if (tid < 64) psh[tid] = 0.f;
    __syncthreads();
#pragma unroll
    for (int it = 0; it < 8; ++it) {
        const int rl = it * 32 + (tid >> 3);
        const int c = (tid & 7) * 8;
        float o[8] = {0.f, 0.f, 0.f, 0.f, 0.f, 0.f, 0.f, 0.f};
#pragma unroll
        for (int s = 0; s < KSPLIT; ++s) {
            const uint4 v = *(const uint4*)(o_split + ((size_t)s * S_LEN + qb + rl) * 64 + c);
            o[0] += bfbits2f(v.x & 0xffff); o[1] += bfbits2f(v.x >> 16);
            o[2] += bfbits2f(v.y & 0xffff); o[3] += bfbits2f(v.y >> 16);
            o[4] += bfbits2f(v.z & 0xffff); o[5] += bfbits2f(v.z >> 16);
            o[6] += bfbits2f(v.w & 0xffff); o[7] += bfbits2f(v.w >> 16);
        }
        const float inv = linv[rl];
#pragma unroll
        for (int j = 0; j < 8; ++j) atomicAdd(&psh[c + j], o[j] * inv);
    }
    __syncthreads();
    if (tid < 64) pool_part[blockIdx.x * 64 + tid] = psh[tid];
    __threadfence();
    if (tid == 0) s_last = (atomicAdd(&counters[32], 1) == 31) ? 1 : 0;
    __syncthreads();
    if (!s_last) return;
    __threadfence();

    // ---- global-last: sum pool partials, conv, project, store ----
    __shared__ float fsh[256];
    {
        float a = 0.f;
        const int e = tid & 63, b0 = (tid >> 6) * 8;
        for (int b = b0; b < b0 + 8; ++b) a += pool_part[b * 64 + e];
        fsh[tid] = a;
    }
    __syncthreads();
    if (tid >= 64) return;

    const int e = tid;
    const float pe = fsh[e] + fsh[64 + e] + fsh[128 + e] + fsh[192 + e];
    int badx = hw_bad(((const unsigned short*)x)[e]);
    int badw = hw_bad(((const unsigned short*)Wq)[e]);
    const int fx = (__ballot(badx) != 0ULL) ? 1 : 0;
    const int fw = (__ballot(badw) != 0ULL) ? 1 : 0;
    const int out_f32 = fx & fw;

    float cv = conv_part[e];
    cv += __shfl_xor(cv, 1); cv += __shfl_xor(cv, 2); cv += __shfl_xor(cv, 4);
    cv += __shfl_xor(cv, 8); cv += __shfl_xor(cv, 16); cv += __shfl_xor(cv, 32);
    const float conv_feat = cv * (1.f / (float)NCONV);
    const float pooled = pe * (1.f / (float)S_LEN) * conv_feat;
    float p0 = pooled * ldin(Wp, e * 4 + 0, fw);
    float p1 = pooled * ldin(Wp, e * 4 + 1, fw);
    float p2 = pooled * ldin(Wp, e * 4 + 2, fw);
    float p3 = pooled * ldin(Wp, e * 4 + 3, fw);
    for (int off = 32; off > 0; off >>= 1) {
        p0 += __shfl_down(p0, off);
        p1 += __shfl_down(p1, off);
        p2 += __shfl_down(p2, off);
        p3 += __shfl_down(p3, off);
    }
    if (e == 0) {
        const float r0 = p0 + ldin(bp, 0, fw);
        const float r1 = p1 + ldin(bp, 1, fw);
        const float r2 = p2 + ldin(bp, 2, fw);
        const float r3 = p3 + ldin(bp, 3, fw);
        if (out_f32) {
            float* oo = (float*)out;
            oo[0] = r0; oo[1] = r1; oo[2] = r2; oo[3] = r3;
        } else {
            __hip_bfloat16* oo = (__hip_bfloat16*)out;
            oo[0] = __float2bfloat16(r0); oo[1] = __float2bfloat16(r1);
            oo[2] = __float2bfloat16(r2); oo[3] = __float2bfloat16(r3);
        }
    }
}

extern "C" void kernel_launch(void* const* d_in, const int* in_sizes, int n_in,
                              void* d_out, int out_size, void* d_ws, size_t ws_size,
                              hipStream_t stream)
{
    const void* x  = d_in[0];
    const void* cw = d_in[1];
    const void* cb = d_in[2];
    const void* Wq = d_in[3];
    const void* bq = d_in[4];
    const void* Wk = d_in[5];
    const void* bk = d_in[6];
    const void* Wv = d_in[7];
    const void* bv = d_in[8];
    const void* Wp = d_in[9];
    const void* bp = d_in[10];

    // ws layout (f32 idx): conv_part[64] | counters[33]@64 | pool_part[32*64]@128 |
    // l_split[KSPLIT*S]@2176 | then bf16: o_split | q | k | vT
    float* ws = (float*)d_ws;
    float* conv_part = ws;
    int*   counters  = (int*)(ws + 64);
    float* pool_part = ws + 128;
    float* l_split   = ws + 128 + 32 * 64;
    unsigned short* o_split = (unsigned short*)(l_split + (size_t)KSPLIT * S_LEN);
    unsigned short* q_bf  = o_split + (size_t)KSPLIT * S_LEN * 64;
    unsigned short* k_bf  = q_bf + (size_t)S_LEN * 64;
    unsigned short* vT_bf = k_bf + (size_t)S_LEN * 64;

    qkv_conv<<<320, 256, 0, stream>>>(x, cw, cb, Wq, bq, Wk, bk, Wv, bv,
                                      q_bf, k_bf, vT_bf, conv_part, counters);
    attn_bf<<<dim3(S_LEN / 256, KSPLIT), 256, 0, stream>>>(
        q_bf, k_bf, vT_bf, o_split, l_split, counters, pool_part, conv_part,
        Wp, bp, x, Wq, d_out);
}

// Round 10
// 132.178 us; speedup vs baseline: 1.4961x; 1.4961x over previous
//
#include <hip/hip_runtime.h>
#include <hip/hip_bf16.h>

#define S_LEN 8192
#define E_DIM 64
#define NCONV (63 * 8191)
#define KSPLIT 32
#define KRANGE (S_LEN / KSPLIT)   // 256 keys per split-block
#define SVT (S_LEN + 32)          // vT_bf row stride (shorts): breaks L1 set aliasing
#define KTS 72                    // kt LDS row stride (shorts)

typedef short short8 __attribute__((ext_vector_type(8)));
typedef float f32x4 __attribute__((ext_vector_type(4)));

__device__ __forceinline__ float ldin(const void* __restrict__ p, int i, int f32flag) {
    return f32flag ? ((const float*)p)[i]
                   : __bfloat162float(((const __hip_bfloat16*)p)[i]);
}
__device__ __forceinline__ float bfbits2f(unsigned int u16bits) {
    union { unsigned int u; float f; } c; c.u = u16bits << 16; return c.f;
}
__device__ __forceinline__ unsigned short f2bfu(float f) {
    __hip_bfloat16 h = __float2bfloat16(f);
    union { __hip_bfloat16 h; unsigned short u; } c; c.h = h; return c.u;
}
__device__ __forceinline__ int hw_bad(unsigned short h) {
    const unsigned int e = (h >> 7) & 0xFF;
    return !(h == 0 || h == 0x8000 || (e >= 0x60 && e <= 0x86));
}

// ---------------- Kernel 1: QKV projection (q pre-scaled by 1/8) + conv + zero accumulators ----------------
// blocks 0..255: qkv, 32 rows each. blocks 256..319: conv partials + zero l_g/w_g/g_pooled/counter.
__global__ __launch_bounds__(256) void qkv_conv(
    const void* __restrict__ x,
    const void* __restrict__ conv_w, const void* __restrict__ conv_b,
    const void* __restrict__ Wq, const void* __restrict__ bq,
    const void* __restrict__ Wk, const void* __restrict__ bk,
    const void* __restrict__ Wv, const void* __restrict__ bv,
    unsigned short* __restrict__ q_bf, unsigned short* __restrict__ k_bf,
    unsigned short* __restrict__ vT_bf, float* __restrict__ conv_part,
    float* __restrict__ l_g, float* __restrict__ w_g,
    float* __restrict__ g_pooled, int* __restrict__ counter)
{
    __shared__ int s_fx, s_fw;
    const int tid = threadIdx.x;
    if (tid == 0) { s_fx = 0; s_fw = 0; }
    __syncthreads();
    if (tid < 64) { if (hw_bad(((const unsigned short*)x)[tid])) atomicOr(&s_fx, 1); }
    else if (tid < 128) { if (hw_bad(((const unsigned short*)Wq)[tid - 64])) atomicOr(&s_fw, 1); }
    __syncthreads();
    const int fx = s_fx, fw = s_fw;

    if (blockIdx.x >= 256) {   // ---- conv + zero path ----
        const int bid = blockIdx.x - 256;
        const int gid = bid * 256 + tid;
        if (gid < 8192) { l_g[gid] = 0.f; w_g[gid] = 0.f; }
        if (gid < 64) g_pooled[gid] = 0.f;
        if (gid == 0) *counter = 0;
        const float c0 = ldin(conv_w, 0, fw), c1 = ldin(conv_w, 1, fw);
        const float c2 = ldin(conv_w, 2, fw), c3 = ldin(conv_w, 3, fw);
        const float cb = ldin(conv_b, 0, fw);
        float acc = 0.f;
        for (int idx = gid; idx < NCONV; idx += 64 * 256) {
            const int h = idx % 63;
            const int w = idx / 63;
            const float z = c0 * ldin(x, w * 64 + h, fx)     + c1 * ldin(x, (w + 1) * 64 + h, fx)
                          + c2 * ldin(x, w * 64 + h + 1, fx) + c3 * ldin(x, (w + 1) * 64 + h + 1, fx)
                          + cb;
            acc += 1.f / (1.f + __expf(-z));
        }
        for (int off = 32; off > 0; off >>= 1) acc += __shfl_down(acc, off);
        __shared__ float wsum[4];
        if ((tid & 63) == 0) wsum[tid >> 6] = acc;
        __syncthreads();
        if (tid == 0) conv_part[bid] = wsum[0] + wsum[1] + wsum[2] + wsum[3];
        return;
    }

    // ---- qkv path (verified R9): weights staged once, 2 row-chunks of 16 ----
    __shared__ float wsh[3][4096];   // 48 KB
    __shared__ float xT[64 * 16];
    __shared__ float bsh[3][64];
    __shared__ float vs[64 * 17];
    const void* Ws[3] = { Wq, Wk, Wv };
    const void* Bs[3] = { bq, bk, bv };
#pragma unroll
    for (int w = 0; w < 3; ++w) {
        if (fw) {
            const float4* src = (const float4*)Ws[w];
            for (int i = tid; i < 1024; i += 256) {
                float4 v = src[i];
                float* d = &wsh[w][i * 4];
                d[0] = v.x; d[1] = v.y; d[2] = v.z; d[3] = v.w;
            }
            if (tid < 64) bsh[w][tid] = ((const float*)Bs[w])[tid];
        } else {
            const uint4* src = (const uint4*)Ws[w];
            for (int i = tid; i < 512; i += 256) {
                uint4 v = src[i];
                float* d = &wsh[w][i * 8];
                d[0] = bfbits2f(v.x & 0xffff); d[1] = bfbits2f(v.x >> 16);
                d[2] = bfbits2f(v.y & 0xffff); d[3] = bfbits2f(v.y >> 16);
                d[4] = bfbits2f(v.z & 0xffff); d[5] = bfbits2f(v.z >> 16);
                d[6] = bfbits2f(v.w & 0xffff); d[7] = bfbits2f(v.w >> 16);
            }
            if (tid < 64) bsh[w][tid] = bfbits2f(((const unsigned short*)Bs[w])[tid]);
        }
    }

#pragma unroll
    for (int ch = 0; ch < 2; ++ch) {
        const int row0 = blockIdx.x * 32 + ch * 16;
        __syncthreads();
        for (int idx = tid; idx < 1024; idx += 256) {
            const int r = idx >> 6, i = idx & 63;
            xT[i * 16 + r] = ldin(x, (row0 + r) * 64 + i, fx);
        }
        __syncthreads();

        const int e = tid & 63, rg = tid >> 6;
        float aq[4], ak[4], av[4];
#pragma unroll
        for (int r = 0; r < 4; ++r) { aq[r] = bsh[0][e]; ak[r] = bsh[1][e]; av[r] = bsh[2][e]; }
#pragma unroll 8
        for (int i = 0; i < 64; ++i) {
            const float4 xv = *(const float4*)&xT[i * 16 + rg * 4];
            const float wq = wsh[0][i * 64 + e], wk = wsh[1][i * 64 + e], wv = wsh[2][i * 64 + e];
            aq[0] += xv.x * wq; aq[1] += xv.y * wq; aq[2] += xv.z * wq; aq[3] += xv.w * wq;
            ak[0] += xv.x * wk; ak[1] += xv.y * wk; ak[2] += xv.z * wk; ak[3] += xv.w * wk;
            av[0] += xv.x * wv; av[1] += xv.y * wv; av[2] += xv.z * wv; av[3] += xv.w * wv;
        }
#pragma unroll
        for (int r = 0; r < 4; ++r) {
            const int row = row0 + rg * 4 + r;
            q_bf[row * 64 + e] = f2bfu(aq[r] * 0.125f);   // fold softmax scale (pow2: exact)
            k_bf[row * 64 + e] = f2bfu(ak[r]);
            vs[e * 17 + rg * 4 + r] = av[r];
        }
        __syncthreads();
        {
            const int e2 = tid >> 2, rp = (tid & 3) * 4;
            const unsigned short h0 = f2bfu(vs[e2 * 17 + rp + 0]);
            const unsigned short h1 = f2bfu(vs[e2 * 17 + rp + 1]);
            const unsigned short h2 = f2bfu(vs[e2 * 17 + rp + 2]);
            const unsigned short h3 = f2bfu(vs[e2 * 17 + rp + 3]);
            uint2 pk;
            pk.x = (unsigned int)h0 | ((unsigned int)h1 << 16);
            pk.y = (unsigned int)h2 | ((unsigned int)h3 << 16);
            *(uint2*)(vT_bf + (size_t)e2 * SVT + row0 + rp) = pk;
        }
    }
}

// ---------------- Kernel 2: pass A — softmax denominators l_r (QK^T + exp + row-sum) ----------------
// Grid (32 q-groups, 32 key-splits). Block: 4 waves x 64 q-rows. No V, no P round-trip.
__global__ __launch_bounds__(256) void attn_l(
    const unsigned short* __restrict__ q_bf, const unsigned short* __restrict__ k_bf,
    float* __restrict__ l_g)
{
    __shared__ unsigned short kt[2][32 * KTS];   // 9216 B
    const int tid = threadIdx.x;
    const int wave = tid >> 6, lane = tid & 63;
    const int ln = lane & 15, quad = lane >> 4;
    const int qrow0 = blockIdx.x * 256 + wave * 64;
    const int kbase = blockIdx.y * KRANGE;

    short8 aQ[4][2];
#pragma unroll
    for (int T = 0; T < 4; ++T) {
        aQ[T][0] = *(const short8*)(q_bf + (qrow0 + 16 * T + ln) * 64 + quad * 8);
        aQ[T][1] = *(const short8*)(q_bf + (qrow0 + 16 * T + ln) * 64 + 32 + quad * 8);
    }
    const f32x4 zero = {0.f, 0.f, 0.f, 0.f};
    float l_acc[4][4];
#pragma unroll
    for (int T = 0; T < 4; ++T)
#pragma unroll
        for (int r = 0; r < 4; ++r) l_acc[T][r] = 0.f;

    const int krow = tid >> 3, kch = tid & 7;
    uint4 kreg;
    {
        const uint4 k0 = *(const uint4*)(k_bf + (size_t)(kbase + krow) * 64 + kch * 8);
        *(uint4*)(&kt[0][krow * KTS + kch * 8]) = k0;
        kreg = *(const uint4*)(k_bf + (size_t)(kbase + 32 + krow) * 64 + kch * 8);
    }
    __syncthreads();

    const int nIter = KRANGE >> 5;   // 8
#pragma unroll 2
    for (int kc = 0; kc < nIter; ++kc) {
        const int cur = kc & 1;
        if (kc + 1 < nIter) *(uint4*)(&kt[cur ^ 1][krow * KTS + kch * 8]) = kreg;
        if (kc + 2 < nIter)
            kreg = *(const uint4*)(k_bf + (size_t)(kbase + (kc + 2) * 32 + krow) * 64 + kch * 8);
        const unsigned short* ktc = &kt[cur][0];
        const short8 bE0 = *(const short8*)(ktc + (2 * ln) * KTS + quad * 8);
        const short8 bE1 = *(const short8*)(ktc + (2 * ln) * KTS + 32 + quad * 8);
        const short8 bO0 = *(const short8*)(ktc + (2 * ln + 1) * KTS + quad * 8);
        const short8 bO1 = *(const short8*)(ktc + (2 * ln + 1) * KTS + 32 + quad * 8);
        f32x4 scE[4], scO[4];
#pragma unroll
        for (int T = 0; T < 4; ++T) {
            scE[T] = __builtin_amdgcn_mfma_f32_16x16x32_bf16(aQ[T][0], bE0, zero, 0, 0, 0);
            scE[T] = __builtin_amdgcn_mfma_f32_16x16x32_bf16(aQ[T][1], bE1, scE[T], 0, 0, 0);
            scO[T] = __builtin_amdgcn_mfma_f32_16x16x32_bf16(aQ[T][0], bO0, zero, 0, 0, 0);
            scO[T] = __builtin_amdgcn_mfma_f32_16x16x32_bf16(aQ[T][1], bO1, scO[T], 0, 0, 0);
        }
#pragma unroll
        for (int T = 0; T < 4; ++T)
#pragma unroll
            for (int r = 0; r < 4; ++r)
                l_acc[T][r] += __expf(scE[T][r]) + __expf(scO[T][r]);
        __syncthreads();
    }

#pragma unroll
    for (int T = 0; T < 4; ++T)
#pragma unroll
        for (int r = 0; r < 4; ++r) {
            float v = l_acc[T][r];
            v += __shfl_xor(v, 1); v += __shfl_xor(v, 2);
            v += __shfl_xor(v, 4); v += __shfl_xor(v, 8);
            if (ln == 0) atomicAdd(&l_g[qrow0 + 16 * T + quad * 4 + r], v);
        }
}

// ---------------- Kernel 3: pass B — w_t = sum_r exp(s_rt)/l_r (QK^T + exp + weighted col-sum) ----------------
__global__ __launch_bounds__(256) void attn_w(
    const unsigned short* __restrict__ q_bf, const unsigned short* __restrict__ k_bf,
    const float* __restrict__ l_g, float* __restrict__ w_g)
{
    __shared__ unsigned short kt[2][32 * KTS];   // 9216 B
    __shared__ float w_sh[4][KRANGE];            // 4 KB
    const int tid = threadIdx.x;
    const int wave = tid >> 6, lane = tid & 63;
    const int ln = lane & 15, quad = lane >> 4;
    const int qrow0 = blockIdx.x * 256 + wave * 64;
    const int kbase = blockIdx.y * KRANGE;

    short8 aQ[4][2];
    float lv[4][4];
#pragma unroll
    for (int T = 0; T < 4; ++T) {
        aQ[T][0] = *(const short8*)(q_bf + (qrow0 + 16 * T + ln) * 64 + quad * 8);
        aQ[T][1] = *(const short8*)(q_bf + (qrow0 + 16 * T + ln) * 64 + 32 + quad * 8);
#pragma unroll
        for (int r = 0; r < 4; ++r)
            lv[T][r] = 1.f / l_g[qrow0 + 16 * T + quad * 4 + r];
    }
    const f32x4 zero = {0.f, 0.f, 0.f, 0.f};

    const int krow = tid >> 3, kch = tid & 7;
    uint4 kreg;
    {
        const uint4 k0 = *(const uint4*)(k_bf + (size_t)(kbase + krow) * 64 + kch * 8);
        *(uint4*)(&kt[0][krow * KTS + kch * 8]) = k0;
        kreg = *(const uint4*)(k_bf + (size_t)(kbase + 32 + krow) * 64 + kch * 8);
    }
    __syncthreads();

    const int nIter = KRANGE >> 5;   // 8
#pragma unroll 2
    for (int kc = 0; kc < nIter; ++kc) {
        const int cur = kc & 1;
        if (kc + 1 < nIter) *(uint4*)(&kt[cur ^ 1][krow * KTS + kch * 8]) = kreg;
        if (kc + 2 < nIter)
            kreg = *(const uint4*)(k_bf + (size_t)(kbase + (kc + 2) * 32 + krow) * 64 + kch * 8);
        const unsigned short* ktc = &kt[cur][0];
        const short8 bE0 = *(const short8*)(ktc + (2 * ln) * KTS + quad * 8);
        const short8 bE1 = *(const short8*)(ktc + (2 * ln) * KTS + 32 + quad * 8);
        const short8 bO0 = *(const short8*)(ktc + (2 * ln + 1) * KTS + quad * 8);
        const short8 bO1 = *(const short8*)(ktc + (2 * ln + 1) * KTS + 32 + quad * 8);
        f32x4 scE[4], scO[4];
#pragma unroll
        for (int T = 0; T < 4; ++T) {
            scE[T] = __builtin_amdgcn_mfma_f32_16x16x32_bf16(aQ[T][0], bE0, zero, 0, 0, 0);
            scE[T] = __builtin_amdgcn_mfma_f32_16x16x32_bf16(aQ[T][1], bE1, scE[T], 0, 0, 0);
            scO[T] = __builtin_amdgcn_mfma_f32_16x16x32_bf16(aQ[T][0], bO0, zero, 0, 0, 0);
            scO[T] = __builtin_amdgcn_mfma_f32_16x16x32_bf16(aQ[T][1], bO1, scO[T], 0, 0, 0);
        }
        float wE = 0.f, wO = 0.f;
#pragma unroll
        for (int T = 0; T < 4; ++T)
#pragma unroll
            for (int r = 0; r < 4; ++r) {
                wE += __expf(scE[T][r]) * lv[T][r];
                wO += __expf(scO[T][r]) * lv[T][r];
            }
        // sum over the 4 quad row-groups (same ln => same key)
        wE += __shfl_xor(wE, 16); wE += __shfl_xor(wE, 32);
        wO += __shfl_xor(wO, 16); wO += __shfl_xor(wO, 32);
        if (lane < 16) {
            w_sh[wave][kc * 32 + 2 * ln]     = wE;
            w_sh[wave][kc * 32 + 2 * ln + 1] = wO;
        }
        __syncthreads();
    }

    for (int k = tid; k < KRANGE; k += 256)
        atomicAdd(&w_g[kbase + k], w_sh[0][k] + w_sh[1][k] + w_sh[2][k] + w_sh[3][k]);
}

// ---------------- Kernel 4: pooled = (w^T V)/S, then conv * proj (last-block finalize) ----------------
__global__ __launch_bounds__(256) void gemv_final(
    const float* __restrict__ w_g, const unsigned short* __restrict__ vT_bf,
    float* __restrict__ g_pooled, int* __restrict__ counter,
    const float* __restrict__ conv_part,
    const void* __restrict__ Wp, const void* __restrict__ bp,
    const void* __restrict__ x, const void* __restrict__ Wq,
    void* __restrict__ out)
{
    __shared__ float psum[64][5];
    const int tid = threadIdx.x;
    const int e = tid >> 2, j = tid & 3;
    const int t0 = blockIdx.x * 256 + j * 64;
    float acc = 0.f;
#pragma unroll
    for (int i = 0; i < 8; ++i) {
        const uint4 v = *(const uint4*)(vT_bf + (size_t)e * SVT + t0 + i * 8);
        const float4 wa = *(const float4*)(w_g + t0 + i * 8);
        const float4 wb = *(const float4*)(w_g + t0 + i * 8 + 4);
        acc += wa.x * bfbits2f(v.x & 0xffff) + wa.y * bfbits2f(v.x >> 16)
             + wa.z * bfbits2f(v.y & 0xffff) + wa.w * bfbits2f(v.y >> 16)
             + wb.x * bfbits2f(v.z & 0xffff) + wb.y * bfbits2f(v.z >> 16)
             + wb.z * bfbits2f(v.w & 0xffff) + wb.w * bfbits2f(v.w >> 16);
    }
    psum[e][j] = acc;
    __syncthreads();
    if (j == 0) atomicAdd(&g_pooled[e], psum[e][0] + psum[e][1] + psum[e][2] + psum[e][3]);
    __threadfence();
    __shared__ int s_last;
    if (tid == 0) s_last = (atomicAdd(counter, 1) == 31) ? 1 : 0;
    __syncthreads();
    if (!s_last || tid >= 64) return;
    __threadfence();

    const int ee = tid;
    int badx = hw_bad(((const unsigned short*)x)[ee]);
    int badw = hw_bad(((const unsigned short*)Wq)[ee]);
    const int fx = (__ballot(badx) != 0ULL) ? 1 : 0;
    const int fw = (__ballot(badw) != 0ULL) ? 1 : 0;
    const int out_f32 = fx & fw;

    float cv = conv_part[ee];
    cv += __shfl_xor(cv, 1); cv += __shfl_xor(cv, 2); cv += __shfl_xor(cv, 4);
    cv += __shfl_xor(cv, 8); cv += __shfl_xor(cv, 16); cv += __shfl_xor(cv, 32);
    const float conv_feat = cv * (1.f / (float)NCONV);
    const float pe = atomicAdd(&g_pooled[ee], 0.f);   // coherent read
    const float pooled = pe * (1.f / (float)S_LEN) * conv_feat;
    float p0 = pooled * ldin(Wp, ee * 4 + 0, fw);
    float p1 = pooled * ldin(Wp, ee * 4 + 1, fw);
    float p2 = pooled * ldin(Wp, ee * 4 + 2, fw);
    float p3 = pooled * ldin(Wp, ee * 4 + 3, fw);
    for (int off = 32; off > 0; off >>= 1) {
        p0 += __shfl_down(p0, off);
        p1 += __shfl_down(p1, off);
        p2 += __shfl_down(p2, off);
        p3 += __shfl_down(p3, off);
    }
    if (ee == 0) {
        const float r0 = p0 + ldin(bp, 0, fw);
        const float r1 = p1 + ldin(bp, 1, fw);
        const float r2 = p2 + ldin(bp, 2, fw);
        const float r3 = p3 + ldin(bp, 3, fw);
        if (out_f32) {
            float* oo = (float*)out;
            oo[0] = r0; oo[1] = r1; oo[2] = r2; oo[3] = r3;
        } else {
            __hip_bfloat16* oo = (__hip_bfloat16*)out;
            oo[0] = __float2bfloat16(r0); oo[1] = __float2bfloat16(r1);
            oo[2] = __float2bfloat16(r2); oo[3] = __float2bfloat16(r3);
        }
    }
}

extern "C" void kernel_launch(void* const* d_in, const int* in_sizes, int n_in,
                              void* d_out, int out_size, void* d_ws, size_t ws_size,
                              hipStream_t stream)
{
    const void* x  = d_in[0];
    const void* cw = d_in[1];
    const void* cb = d_in[2];
    const void* Wq = d_in[3];
    const void* bq = d_in[4];
    const void* Wk = d_in[5];
    const void* bk = d_in[6];
    const void* Wv = d_in[7];
    const void* bv = d_in[8];
    const void* Wp = d_in[9];
    const void* bp = d_in[10];

    // ws layout (f32 idx): g_pooled[64] | counter@64 | conv_part@128..191 |
    // l_g@256 (8192) | w_g@8448 (8192) | then bf16: q_bf | k_bf | vT_bf
    float* ws = (float*)d_ws;
    float* g_pooled  = ws;
    int*   counter   = (int*)(ws + 64);
    float* conv_part = ws + 128;
    float* l_g       = ws + 256;
    float* w_g       = ws + 256 + 8192;
    unsigned short* q_bf  = (unsigned short*)(ws + 256 + 2 * 8192);
    unsigned short* k_bf  = q_bf + (size_t)S_LEN * 64;
    unsigned short* vT_bf = k_bf + (size_t)S_LEN * 64;

    qkv_conv<<<320, 256, 0, stream>>>(x, cw, cb, Wq, bq, Wk, bk, Wv, bv,
                                      q_bf, k_bf, vT_bf, conv_part,
                                      l_g, w_g, g_pooled, counter);
    attn_l<<<dim3(32, KSPLIT), 256, 0, stream>>>(q_bf, k_bf, l_g);
    attn_w<<<dim3(32, KSPLIT), 256, 0, stream>>>(q_bf, k_bf, l_g, w_g);
    gemv_final<<<32, 256, 0, stream>>>(w_g, vT_bf, g_pooled, counter, conv_part,
                                       Wp, bp, x, Wq, d_out);
}